// Round 2
// baseline (1308.834 us; speedup 1.0000x reference)
//
#include <hip/hip_runtime.h>
#include <math.h>

#define CH 128
#define SCAN_T 256
#define SCAN_I 4
#define SCAN_CHUNK (SCAN_T * SCAN_I)

// bucket partition for CSR fill
#define BSHIFT 9                 // 512 nodes per bucket
#define BREP 8                   // 8-way replicated frontiers to cut atomic contention

typedef __attribute__((ext_vector_type(8))) short bf16x8;
typedef __attribute__((ext_vector_type(4))) float f32x4;

// ---------------- CSR build ----------------
// counts per node AND per (sign,bucket,rep) sub-bucket
__global__ void count_kernel(const int* __restrict__ pd, const int* __restrict__ nd,
                             int* __restrict__ cnt_p, int* __restrict__ cnt_n,
                             int* __restrict__ bcnt, int NBr, int E) {
    int i = blockIdx.x * blockDim.x + threadIdx.x;
    if (i < E) {
        int d = pd[i];
        atomicAdd(&cnt_p[d], 1);
        atomicAdd(&bcnt[((d >> BSHIFT) << 3) | (i & (BREP - 1))], 1);
    } else if (i < 2 * E) {
        int k = i - E;
        int d = nd[k];
        atomicAdd(&cnt_n[d], 1);
        atomicAdd(&bcnt[((NBr + (d >> BSHIFT)) << 3) | (k & (BREP - 1))], 1);
    }
}

__global__ __launch_bounds__(SCAN_T) void partial_kernel(const int* __restrict__ cnt, int n,
                                                         int* __restrict__ partials) {
    const int y = blockIdx.y, b = blockIdx.x, t = threadIdx.x;
    const int* c = cnt + (size_t)y * n;
    const int base = b * SCAN_CHUNK + t * SCAN_I;
    int s = 0;
    if (base + SCAN_I <= n) {
        int4 v = *(const int4*)(c + base);
        s = v.x + v.y + v.z + v.w;
    } else {
        for (int i = 0; i < SCAN_I; ++i)
            if (base + i < n) s += c[base + i];
    }
    __shared__ int red[SCAN_T];
    red[t] = s;
    __syncthreads();
    for (int off = SCAN_T / 2; off > 0; off >>= 1) {
        if (t < off) red[t] += red[t + off];
        __syncthreads();
    }
    if (t == 0) partials[y * 256 + b] = red[0];
}

__global__ __launch_bounds__(256) void scan_partials_kernel(int* __restrict__ partials, int nb) {
    const int y = blockIdx.y, t = threadIdx.x;
    int* p = partials + y * 256;
    __shared__ int sh[256];
    sh[t] = (t < nb) ? p[t] : 0;
    __syncthreads();
    for (int off = 1; off < 256; off <<= 1) {
        int v = (t >= off) ? sh[t - off] : 0;
        __syncthreads();
        sh[t] += v;
        __syncthreads();
    }
    if (t < nb) p[t] = (t == 0) ? 0 : sh[t - 1];
}

// row offsets only (per-node cur lives in LDS of fillp2 now)
__global__ __launch_bounds__(SCAN_T) void scan_apply_kernel(const int* __restrict__ cnt, int n,
                                                            const int* __restrict__ partials,
                                                            int* __restrict__ row, int total) {
    const int y = blockIdx.y, b = blockIdx.x, t = threadIdx.x;
    const int* c = cnt + (size_t)y * n;
    int* r = row + (size_t)y * (n + 1);
    const int base = b * SCAN_CHUNK + t * SCAN_I;
    int v0 = 0, v1 = 0, v2 = 0, v3 = 0;
    const bool full = (base + SCAN_I <= n);
    if (full) {
        int4 vv = *(const int4*)(c + base);
        v0 = vv.x; v1 = vv.y; v2 = vv.z; v3 = vv.w;
    } else {
        if (base + 0 < n) v0 = c[base + 0];
        if (base + 1 < n) v1 = c[base + 1];
        if (base + 2 < n) v2 = c[base + 2];
        if (base + 3 < n) v3 = c[base + 3];
    }
    const int s = v0 + v1 + v2 + v3;
    __shared__ int sh[SCAN_T];
    sh[t] = s;
    __syncthreads();
    for (int off = 1; off < SCAN_T; off <<= 1) {
        int v = (t >= off) ? sh[t - off] : 0;
        __syncthreads();
        sh[t] += v;
        __syncthreads();
    }
    int run = partials[y * 256 + b] + sh[t] - s;
    if (full) {
        int4 rv;
        rv.x = run; rv.y = run + v0; rv.z = run + v0 + v1; rv.w = run + v0 + v1 + v2;
        *(int4*)(r + base) = rv;
    } else {
        if (base + 0 < n) { r[base + 0] = run; run += v0; }
        if (base + 1 < n) { r[base + 1] = run; run += v1; }
        if (base + 2 < n) { r[base + 2] = run; run += v2; }
        if (base + 3 < n) { r[base + 3] = run; run += v3; }
    }
    if (b == 0 && t == 0) r[n] = total;
}

// exclusive scan over the ktot sub-bucket counts (ktot <= 4096), one block
__global__ __launch_bounds__(1024) void bscan_kernel(const int* __restrict__ bcnt, int ktot,
                                                     int total, int* __restrict__ boff,
                                                     int* __restrict__ bcur) {
    const int t = threadIdx.x;
    const int base = t * 4;
    int v[4];
    int s = 0;
#pragma unroll
    for (int j = 0; j < 4; ++j) {
        int x = (base + j < ktot) ? bcnt[base + j] : 0;
        v[j] = s;
        s += x;
    }
    __shared__ int sh[1024];
    sh[t] = s;
    __syncthreads();
    for (int off = 1; off < 1024; off <<= 1) {
        int u = (t >= off) ? sh[t - off] : 0;
        __syncthreads();
        sh[t] += u;
        __syncthreads();
    }
    int run = sh[t] - s;  // exclusive prefix of this thread's chunk
#pragma unroll
    for (int j = 0; j < 4; ++j) {
        if (base + j < ktot) {
            int o = run + v[j];
            boff[base + j] = o;
            bcur[base + j] = o;
        }
    }
    if (t == 0) boff[ktot] = total;
}

// phase 1: scatter (src,dst) into bucket-partitioned temp. ~3100 hot write
// frontiers device-wide -> write-back lines are full (coalesced at HBM).
__global__ void fillp1_kernel(const int* __restrict__ pe, const int* __restrict__ ne,
                              int* __restrict__ bcur, int2* __restrict__ tmp,
                              int NBr, int E) {
    int i = blockIdx.x * blockDim.x + threadIdx.x;
    int s, d, key;
    if (i < E) {
        s = pe[i]; d = pe[E + i];
        key = ((d >> BSHIFT) << 3) | (i & (BREP - 1));
    } else if (i < 2 * E) {
        int k = i - E;
        s = ne[k]; d = ne[E + k];
        key = ((NBr + (d >> BSHIFT)) << 3) | (k & (BREP - 1));
    } else {
        return;
    }
    int p = atomicAdd(&bcur[key], 1);
    tmp[p] = make_int2(s, d);
}

// phase 2: one block per (bucket,sign). Per-node write cursors in LDS; all
// csr writes land in the bucket's ~24KB contiguous row range (L2-resident).
__global__ __launch_bounds__(256) void fillp2_kernel(const int2* __restrict__ tmp,
                                                     const int* __restrict__ boff,
                                                     const int* __restrict__ row_p,
                                                     const int* __restrict__ row_n,
                                                     int* __restrict__ csr_p,
                                                     int* __restrict__ csr_n,
                                                     int NBr, int nN) {
    const int b = blockIdx.x;
    const int sign = blockIdx.y;
    const int t = threadIdx.x;
    const int* __restrict__ row = sign ? row_n : row_p;
    int* __restrict__ csr = sign ? csr_n : csr_p;
    const int base = b << BSHIFT;
    const int nloc = min(1 << BSHIFT, nN - base);
    __shared__ int cur[1 << BSHIFT];
    for (int i = t; i < nloc; i += 256) cur[i] = row[base + i];
    __syncthreads();
    const int k0 = (sign * NBr + b) << 3;
    const int lo = boff[k0], hi = boff[k0 + BREP];
    for (int e = lo + t; e < hi; e += 256) {
        int2 ed = tmp[e];
        int p = atomicAdd(&cur[ed.y - base], 1);
        csr[p] = ed.x;
    }
}

// ---------------- helpers ----------------
__device__ __forceinline__ float fast_tanh(float x) {
    float e = __expf(2.0f * x);
    return 1.0f - 2.0f * __builtin_amdgcn_rcpf(e + 1.0f);
}

__device__ __forceinline__ unsigned short f2bf(float f) {  // RNE
    unsigned u = __float_as_uint(f);
    u += 0x7fffu + ((u >> 16) & 1u);
    return (unsigned short)(u >> 16);
}

__device__ __forceinline__ float bf_lo(unsigned v) { return __uint_as_float(v << 16); }
__device__ __forceinline__ float bf_hi(unsigned v) { return __uint_as_float(v & 0xffff0000u); }

// ---------------- aggregate ----------------
// One wave per (node, sign). No LDS, low VGPR, edge loop unrolled x8.
// lane covers channels (2*lane, 2*lane+1); output packed bf16 dword.
template <bool FP32IN>
__global__ __launch_bounds__(256) void agg_kernel(
    const void* __restrict__ featv,
    unsigned* __restrict__ aggp, unsigned* __restrict__ aggn,
    const int* __restrict__ row_p, const int* __restrict__ csr_p,
    const int* __restrict__ row_n, const int* __restrict__ csr_n, int nN) {
    const int t = threadIdx.x;
    const int wave = __builtin_amdgcn_readfirstlane(t >> 6);
    const int lane = t & 63;
    const int node = blockIdx.x * 2 + (wave >> 1);
    const int sign = wave & 1;
    if (node >= nN) return;
    const int* __restrict__ rowp = sign ? row_n : row_p;
    const int* __restrict__ csr = sign ? csr_n : csr_p;
    unsigned* __restrict__ out = sign ? aggn : aggp;
    const int s0 = rowp[node], s1 = rowp[node + 1];
    float ax = 0.f, ay = 0.f;
    int e = s0;
    if (FP32IN) {
        const float* feat = (const float*)featv;
        for (; e + 7 < s1; e += 8) {
            const int a0 = csr[e], a1 = csr[e+1], a2 = csr[e+2], a3 = csr[e+3];
            const int a4 = csr[e+4], a5 = csr[e+5], a6 = csr[e+6], a7 = csr[e+7];
            const float2 v0 = ((const float2*)(feat + (size_t)a0 * CH))[lane];
            const float2 v1 = ((const float2*)(feat + (size_t)a1 * CH))[lane];
            const float2 v2 = ((const float2*)(feat + (size_t)a2 * CH))[lane];
            const float2 v3 = ((const float2*)(feat + (size_t)a3 * CH))[lane];
            const float2 v4 = ((const float2*)(feat + (size_t)a4 * CH))[lane];
            const float2 v5 = ((const float2*)(feat + (size_t)a5 * CH))[lane];
            const float2 v6 = ((const float2*)(feat + (size_t)a6 * CH))[lane];
            const float2 v7 = ((const float2*)(feat + (size_t)a7 * CH))[lane];
            ax += ((v0.x + v1.x) + (v2.x + v3.x)) + ((v4.x + v5.x) + (v6.x + v7.x));
            ay += ((v0.y + v1.y) + (v2.y + v3.y)) + ((v4.y + v5.y) + (v6.y + v7.y));
        }
        for (; e + 1 < s1; e += 2) {
            const int a0 = csr[e], a1 = csr[e + 1];
            const float2 v0 = ((const float2*)(feat + (size_t)a0 * CH))[lane];
            const float2 v1 = ((const float2*)(feat + (size_t)a1 * CH))[lane];
            ax += v0.x + v1.x;
            ay += v0.y + v1.y;
        }
        if (e < s1) {
            const float2 v0 = ((const float2*)(feat + (size_t)csr[e] * CH))[lane];
            ax += v0.x; ay += v0.y;
        }
    } else {
        const unsigned short* feat = (const unsigned short*)featv;
        for (; e + 7 < s1; e += 8) {
            const int a0 = csr[e], a1 = csr[e+1], a2 = csr[e+2], a3 = csr[e+3];
            const int a4 = csr[e+4], a5 = csr[e+5], a6 = csr[e+6], a7 = csr[e+7];
            const unsigned v0 = ((const unsigned*)(feat + (size_t)a0 * CH))[lane];
            const unsigned v1 = ((const unsigned*)(feat + (size_t)a1 * CH))[lane];
            const unsigned v2 = ((const unsigned*)(feat + (size_t)a2 * CH))[lane];
            const unsigned v3 = ((const unsigned*)(feat + (size_t)a3 * CH))[lane];
            const unsigned v4 = ((const unsigned*)(feat + (size_t)a4 * CH))[lane];
            const unsigned v5 = ((const unsigned*)(feat + (size_t)a5 * CH))[lane];
            const unsigned v6 = ((const unsigned*)(feat + (size_t)a6 * CH))[lane];
            const unsigned v7 = ((const unsigned*)(feat + (size_t)a7 * CH))[lane];
            ax += ((bf_lo(v0) + bf_lo(v1)) + (bf_lo(v2) + bf_lo(v3))) +
                  ((bf_lo(v4) + bf_lo(v5)) + (bf_lo(v6) + bf_lo(v7)));
            ay += ((bf_hi(v0) + bf_hi(v1)) + (bf_hi(v2) + bf_hi(v3))) +
                  ((bf_hi(v4) + bf_hi(v5)) + (bf_hi(v6) + bf_hi(v7)));
        }
        for (; e + 1 < s1; e += 2) {
            const unsigned v0 = ((const unsigned*)(feat + (size_t)csr[e] * CH))[lane];
            const unsigned v1 = ((const unsigned*)(feat + (size_t)csr[e + 1] * CH))[lane];
            ax += bf_lo(v0) + bf_lo(v1);
            ay += bf_hi(v0) + bf_hi(v1);
        }
        if (e < s1) {
            const unsigned v0 = ((const unsigned*)(feat + (size_t)csr[e] * CH))[lane];
            ax += bf_lo(v0); ay += bf_hi(v0);
        }
    }
    const int d = s1 - s0;
    const float inv = 1.0f / (float)(d > 1 ? d : 1);
    ax *= inv; ay *= inv;
    out[(size_t)node * 64 + lane] = (unsigned)f2bf(ax) | ((unsigned)f2bf(ay) << 16);
}

// ---------------- weight packing ----------------
// Wcat[384x128] per layer -> MFMA B-frag layout:
// packed[(L*12+ks)*8+nt][lane][j] = Wcat[ks*32+(lane>>4)*8+j][nt*16+(lane&15)]
__global__ __launch_bounds__(64) void wpack_kernel(
    const float* __restrict__ Wp_l, const float* __restrict__ Wp_r,
    const float* __restrict__ Wn_l, const float* __restrict__ Wn_r,
    const float* __restrict__ Wl_pos, const float* __restrict__ Wr_pos,
    const float* __restrict__ Wl_neg, const float* __restrict__ Wr_neg,
    unsigned short* __restrict__ Wpk) {
    const int b = blockIdx.x;  // 0..287 = L*96 + ks*8 + nt
    const int L = b / 96;
    const int rem = b % 96;
    const int ks = rem / 8, nt = rem % 8;
    const int lane = threadIdx.x;
    const int kb = ks * 32 + (lane >> 4) * 8;
    const int n = nt * 16 + (lane & 15);
    unsigned short v[8];
#pragma unroll
    for (int j = 0; j < 8; ++j) {
        const int k = kb + j;
        float w = 0.f;
        if (L == 0) {
            if (k < 128)      w = (n < 64) ? Wp_l[k * 64 + n] : 0.f;
            else if (k < 256) w = (n < 64) ? 0.f : Wn_l[(k - 128) * 64 + (n - 64)];
            else              w = (n < 64) ? Wp_r[(k - 256) * 64 + n]
                                           : Wn_r[(k - 256) * 64 + (n - 64)];
        } else {
            const float* WLp = Wl_pos + (size_t)(L - 1) * 128 * 64;
            const float* WLn = Wl_neg + (size_t)(L - 1) * 128 * 64;
            const float* WRp = Wr_pos + (size_t)(L - 1) * 64 * 64;
            const float* WRn = Wr_neg + (size_t)(L - 1) * 64 * 64;
            if (k < 64)       w = (n < 64) ? WLp[k * 64 + n] : 0.f;
            else if (k < 128) w = (n < 64) ? 0.f : WLn[(k - 64) * 64 + (n - 64)];
            else if (k < 192) w = (n < 64) ? 0.f : WLn[(64 + k - 128) * 64 + (n - 64)];
            else if (k < 256) w = (n < 64) ? WLp[(64 + k - 192) * 64 + n] : 0.f;
            else if (k < 320) w = (n < 64) ? WRp[(k - 256) * 64 + n] : 0.f;
            else              w = (n < 64) ? 0.f : WRn[(k - 320) * 64 + (n - 64)];
        }
        v[j] = f2bf(w);
    }
    unsigned short* dst = Wpk + (size_t)b * 512 + lane * 8;
#pragma unroll
    for (int j = 0; j < 8; ++j) dst[j] = v[j];
}

__global__ void bcat_kernel(const float* __restrict__ bp, const float* __restrict__ bn,
                            const float* __restrict__ b_pos, const float* __restrict__ b_neg,
                            float* __restrict__ bcat) {
    int t = threadIdx.x;  // 384
    int L = t >> 7, n = t & 127;
    float v;
    if (L == 0) v = (n < 64) ? bp[n] : bn[n - 64];
    else        v = (n < 64) ? b_pos[(L - 1) * 64 + n] : b_neg[(L - 1) * 64 + (n - 64)];
    bcat[t] = v;
}

// ---------------- MFMA GEMM: z = tanh([aggp|aggn|feat] @ Wcat + bcat) ----------------
// Block = 4 waves, 64 rows; wave -> 16 rows, full 128 cols (8 n-tiles).
// A-frag: lane holds A[r0+(lane&15)][kcol + (lane>>4)*8 + j]  (m120-verified layout)
// B-frag: from packed buffer (built to match)
// C/D:    col = lane&15, row = r0 + (lane>>4)*4 + reg        (m89-verified layout)
// In-place safe: block reads only its own 64 rows before its stores.
template <bool XF32, bool OUTF32>
__global__ __launch_bounds__(256) void gemm_kernel(
    const unsigned short* __restrict__ aggp, const unsigned short* __restrict__ aggn,
    const void* __restrict__ featv, const unsigned short* __restrict__ Wpk,
    const float* __restrict__ bcat, void* __restrict__ outv, int nN) {
    const int t = threadIdx.x;
    const int wave = __builtin_amdgcn_readfirstlane(t >> 6);
    const int lane = t & 63;
    const int r0 = blockIdx.x * 64 + wave * 16;
    int rowA = r0 + (lane & 15);
    if (rowA >= nN) rowA = nN - 1;  // clamp loads; stores guarded
    const int koff = (lane >> 4) * 8;

    f32x4 acc[8];
#pragma unroll
    for (int i = 0; i < 8; ++i) acc[i] = (f32x4){0.f, 0.f, 0.f, 0.f};

#pragma unroll
    for (int ks = 0; ks < 12; ++ks) {
        const int kcol = (ks & 3) * 32 + koff;
        bf16x8 a;
        if (ks < 4) {
            a = *(const bf16x8*)(aggp + (size_t)rowA * CH + kcol);
        } else if (ks < 8) {
            a = *(const bf16x8*)(aggn + (size_t)rowA * CH + kcol);
        } else if (XF32) {
            const float* p = (const float*)featv + (size_t)rowA * CH + kcol;
            const float4 u0 = *(const float4*)(p);
            const float4 u1 = *(const float4*)(p + 4);
            union { bf16x8 v; unsigned short u[8]; } au;
            au.u[0] = f2bf(u0.x); au.u[1] = f2bf(u0.y);
            au.u[2] = f2bf(u0.z); au.u[3] = f2bf(u0.w);
            au.u[4] = f2bf(u1.x); au.u[5] = f2bf(u1.y);
            au.u[6] = f2bf(u1.z); au.u[7] = f2bf(u1.w);
            a = au.v;
        } else {
            a = *(const bf16x8*)((const unsigned short*)featv + (size_t)rowA * CH + kcol);
        }
        const unsigned short* wb = Wpk + (size_t)(ks * 8) * 512 + lane * 8;
#pragma unroll
        for (int nt = 0; nt < 8; ++nt) {
            const bf16x8 bfr = *(const bf16x8*)(wb + nt * 512);
            acc[nt] = __builtin_amdgcn_mfma_f32_16x16x32_bf16(a, bfr, acc[nt], 0, 0, 0);
        }
    }

    const int col0 = lane & 15;
    const int rq = (lane >> 4) * 4;
#pragma unroll
    for (int nt = 0; nt < 8; ++nt) {
        const int col = nt * 16 + col0;
        const float bias = bcat[col];
#pragma unroll
        for (int r = 0; r < 4; ++r) {
            const int row = r0 + rq + r;
            if (row < nN) {
                const float v = fast_tanh(acc[nt][r] + bias);
                if (OUTF32) ((float*)outv)[(size_t)row * CH + col] = v;
                else ((unsigned short*)outv)[(size_t)row * CH + col] = f2bf(v);
            }
        }
    }
}

// ---------------- launch ----------------
extern "C" void kernel_launch(void* const* d_in, const int* in_sizes, int n_in,
                              void* d_out, int out_size, void* d_ws, size_t ws_size,
                              hipStream_t stream) {
    const float* x      = (const float*)d_in[0];
    const int*   pe     = (const int*)d_in[1];  // [2][E] src,dst
    const int*   ne     = (const int*)d_in[2];
    const float* Wp_l   = (const float*)d_in[3];
    const float* Wp_r   = (const float*)d_in[4];
    const float* bp     = (const float*)d_in[5];
    const float* Wn_l   = (const float*)d_in[6];
    const float* Wn_r   = (const float*)d_in[7];
    const float* bn     = (const float*)d_in[8];
    const float* Wl_pos = (const float*)d_in[9];
    const float* Wr_pos = (const float*)d_in[10];
    const float* b_pos  = (const float*)d_in[11];
    const float* Wl_neg = (const float*)d_in[12];
    const float* Wr_neg = (const float*)d_in[13];
    const float* b_neg  = (const float*)d_in[14];

    const int E = in_sizes[1] / 2;
    const int n = in_sizes[0] / CH;

    const int NBr  = (n + (1 << BSHIFT) - 1) >> BSHIFT;  // buckets per sign
    const int KTOT = 2 * NBr * BREP;                     // sub-bucket count

    // workspace layout
    unsigned short* A    = (unsigned short*)d_ws;   // n*128 bf16
    unsigned short* B    = A + (size_t)n * CH;
    unsigned short* C    = B + (size_t)n * CH;
    unsigned short* Wpk  = C + (size_t)n * CH;      // 3*96*512 = 147456
    float* bcat  = (float*)(Wpk + 147456);          // 384
    int* cnt_p   = (int*)(bcat + 384);              // n
    int* cnt_n   = cnt_p + n;                       // n
    int* bcnt    = cnt_n + n;                       // KTOT (zeroed with cnt)
    int* row_p   = bcnt + KTOT;                     // n+1
    int* row_n   = row_p + n + 1;                   // n+1
    int* csr_p   = row_n + n + 1;                   // E
    int* csr_n   = csr_p + E;                       // E
    int* partials = csr_n + E;                      // 512
    int* boff    = partials + 512;                  // KTOT+1
    int* bcur    = boff + KTOT + 1;                 // KTOT
    // temp edge buffer (2E int2 = 16*E bytes) aliases C: C is first written by
    // layer-1 agg, strictly after fillp2 completes (stream order) -> safe.
    int2* tmp    = (int2*)C;

    hipMemsetAsync(cnt_p, 0, ((size_t)2 * n + KTOT) * sizeof(int), stream);

    const int eb = 256, eg2 = (2 * E + eb - 1) / eb;
    const int nb = (n + SCAN_CHUNK - 1) / SCAN_CHUNK;

    count_kernel<<<eg2, eb, 0, stream>>>(pe + E, ne + E, cnt_p, cnt_n, bcnt, NBr, E);
    wpack_kernel<<<288, 64, 0, stream>>>(Wp_l, Wp_r, Wn_l, Wn_r,
                                         Wl_pos, Wr_pos, Wl_neg, Wr_neg, Wpk);
    bcat_kernel<<<1, 384, 0, stream>>>(bp, bn, b_pos, b_neg, bcat);
    partial_kernel<<<dim3(nb, 2), SCAN_T, 0, stream>>>(cnt_p, n, partials);
    scan_partials_kernel<<<dim3(1, 2), 256, 0, stream>>>(partials, nb);
    scan_apply_kernel<<<dim3(nb, 2), SCAN_T, 0, stream>>>(cnt_p, n, partials, row_p, E);
    bscan_kernel<<<1, 1024, 0, stream>>>(bcnt, KTOT, 2 * E, boff, bcur);
    fillp1_kernel<<<eg2, eb, 0, stream>>>(pe, ne, bcur, tmp, NBr, E);
    fillp2_kernel<<<dim3(NBr, 2), 256, 0, stream>>>(tmp, boff, row_p, row_n,
                                                    csr_p, csr_n, NBr, n);

    const dim3 agrid((n + 1) / 2), ablock(256);
    const dim3 ggrid((n + 63) / 64), gblock(256);

    // L0: agg(x) -> A,B ; gemm(A,B,x) -> z1 in A
    agg_kernel<true><<<agrid, ablock, 0, stream>>>(
        x, (unsigned*)A, (unsigned*)B, row_p, csr_p, row_n, csr_n, n);
    gemm_kernel<true, false><<<ggrid, gblock, 0, stream>>>(
        A, B, x, Wpk, bcat, A, n);
    // L1: agg(A) -> B,C ; gemm(B,C,A) -> z2 in B
    agg_kernel<false><<<agrid, ablock, 0, stream>>>(
        A, (unsigned*)B, (unsigned*)C, row_p, csr_p, row_n, csr_n, n);
    gemm_kernel<false, false><<<ggrid, gblock, 0, stream>>>(
        B, C, A, Wpk + 96 * 512, bcat + 128, B, n);
    // L2: agg(B) -> A,C ; gemm(A,C,B) -> d_out fp32
    agg_kernel<false><<<agrid, ablock, 0, stream>>>(
        B, (unsigned*)A, (unsigned*)C, row_p, csr_p, row_n, csr_n, n);
    gemm_kernel<false, true><<<ggrid, gblock, 0, stream>>>(
        A, C, B, Wpk + 2 * 96 * 512, bcat + 256, d_out, n);
}

// Round 3
// 694.696 us; speedup vs baseline: 1.8840x; 1.8840x over previous
//
#include <hip/hip_runtime.h>
#include <math.h>

#define CH 128
#define BSHIFT 9                  // 512 nodes per bucket
#define BNODES (1 << BSHIFT)
#define CHUNKE 16384              // edges per hist/scatter block

typedef __attribute__((ext_vector_type(8))) short bf16x8;
typedef __attribute__((ext_vector_type(4))) float f32x4;

// ---------------- CSR build: atomic-free counting sort ----------------
// Phase 1: per-(chunk,sign) LDS histogram over node-buckets.
// hb layout per sign: [bucket][block]  (b*G+g), M = NBr*G entries.
__global__ __launch_bounds__(256) void hist_kernel(const int* __restrict__ pe,
                                                   const int* __restrict__ ne,
                                                   int* __restrict__ hb,
                                                   int NBr, int G, int M, int E) {
    const int g = blockIdx.x, s = blockIdx.y, t = threadIdx.x;
    const int* __restrict__ dst = (s ? ne : pe) + E;
    __shared__ int h[512];                      // NBr <= 512 (n <= 256K)
    for (int i = t; i < NBr; i += 256) h[i] = 0;
    __syncthreads();
    const int e0 = g * CHUNKE, e1 = min(e0 + CHUNKE, E);
    for (int e = e0 + t; e < e1; e += 256) atomicAdd(&h[dst[e] >> BSHIFT], 1);
    __syncthreads();
    int* out = hb + (size_t)s * M;
    for (int b = t; b < NBr; b += 256) out[b * G + g] = h[b];
}

// Phase 2: exclusive scan of the M-entry histogram, one block per sign.
__global__ __launch_bounds__(1024) void hscan_kernel(int* __restrict__ hb, int M) {
    const int s = blockIdx.y, t = threadIdx.x;
    int* H = hb + (size_t)s * M;
    const int K = (M + 1023) >> 10;
    const int i0 = t * K, i1 = min(i0 + K, M);
    int sum = 0;
    for (int i = i0; i < i1; ++i) sum += H[i];
    __shared__ int sh[1024];
    sh[t] = sum;
    __syncthreads();
    for (int off = 1; off < 1024; off <<= 1) {
        int v = (t >= off) ? sh[t - off] : 0;
        __syncthreads();
        sh[t] += v;
        __syncthreads();
    }
    int run = sh[t] - sum;
    for (int i = i0; i < i1; ++i) { int v = H[i]; H[i] = run; run += v; }
}

// Phase 3: scatter edges into bucket-contiguous tmp, packed (src<<BSHIFT)|dloc.
// LDS cursors from scanned hist -> deterministic slots, no global atomics.
__global__ __launch_bounds__(256) void scatter_kernel(const int* __restrict__ pe,
                                                      const int* __restrict__ ne,
                                                      const int* __restrict__ hb,
                                                      int* __restrict__ tmp,
                                                      int NBr, int G, int M, int E) {
    const int g = blockIdx.x, s = blockIdx.y, t = threadIdx.x;
    const int* __restrict__ ed = s ? ne : pe;
    const int* off = hb + (size_t)s * M;
    __shared__ int cur[512];
    for (int b = t; b < NBr; b += 256) cur[b] = off[b * G + g];
    __syncthreads();
    int* out = tmp + (size_t)s * E;
    const int e0 = g * CHUNKE, e1 = min(e0 + CHUNKE, E);
    for (int e = e0 + t; e < e1; e += 256) {
        const int src = ed[e], d = ed[E + e];
        const int p = atomicAdd(&cur[d >> BSHIFT], 1);   // LDS atomic
        out[p] = (src << BSHIFT) | (d & (BNODES - 1));
    }
}

// Phase 4: one block per (bucket,sign). Degree-count in LDS, LDS scan of 512
// -> row offsets written directly (replaces global scan kernels); then scatter
// csr within the bucket's contiguous (L2-resident) range.
__global__ __launch_bounds__(256) void bucket_kernel(const int* __restrict__ tmp,
                                                     const int* __restrict__ hb,
                                                     int* __restrict__ row_p,
                                                     int* __restrict__ row_n,
                                                     int* __restrict__ csr_p,
                                                     int* __restrict__ csr_n,
                                                     int NBr, int G, int M, int E, int nN) {
    const int b = blockIdx.x, s = blockIdx.y, t = threadIdx.x;
    const int* off = hb + (size_t)s * M;
    const int lo = off[b * G];
    const int hi = (b + 1 < NBr) ? off[(b + 1) * G] : E;
    const int base = b << BSHIFT;
    const int nloc = min(BNODES, nN - base);
    const int* __restrict__ in = tmp + (size_t)s * E;
    int* __restrict__ row = s ? row_n : row_p;
    int* __restrict__ csr = s ? csr_n : csr_p;
    __shared__ int cnt[BNODES];
    __shared__ int psum[256];
    for (int i = t; i < BNODES; i += 256) cnt[i] = 0;
    __syncthreads();
    for (int e = lo + t; e < hi; e += 256) atomicAdd(&cnt[in[e] & (BNODES - 1)], 1);
    __syncthreads();
    // exclusive scan of cnt[0..512): 2 elems/thread + Hillis-Steele over pairs
    const int c0 = cnt[2 * t], c1 = cnt[2 * t + 1];
    const int ps = c0 + c1;
    psum[t] = ps;
    __syncthreads();
    for (int o = 1; o < 256; o <<= 1) {
        int v = (t >= o) ? psum[t - o] : 0;
        __syncthreads();
        psum[t] += v;
        __syncthreads();
    }
    const int ex = psum[t] - ps;
    cnt[2 * t]     = lo + ex;        // becomes write cursor
    cnt[2 * t + 1] = lo + ex + c0;
    if (2 * t < nloc)     row[base + 2 * t] = lo + ex;
    if (2 * t + 1 < nloc) row[base + 2 * t + 1] = lo + ex + c0;
    if (b == NBr - 1 && t == 0) row[nN] = E;
    __syncthreads();
    for (int e = lo + t; e < hi; e += 256) {
        const int v = in[e];
        const int p = atomicAdd(&cnt[v & (BNODES - 1)], 1);  // LDS atomic
        csr[p] = v >> BSHIFT;
    }
}

// ---------------- helpers ----------------
__device__ __forceinline__ float fast_tanh(float x) {
    float e = __expf(2.0f * x);
    return 1.0f - 2.0f * __builtin_amdgcn_rcpf(e + 1.0f);
}

__device__ __forceinline__ unsigned short f2bf(float f) {  // RNE
    unsigned u = __float_as_uint(f);
    u += 0x7fffu + ((u >> 16) & 1u);
    return (unsigned short)(u >> 16);
}

__device__ __forceinline__ float bf_lo(unsigned v) { return __uint_as_float(v << 16); }
__device__ __forceinline__ float bf_hi(unsigned v) { return __uint_as_float(v & 0xffff0000u); }

// ---------------- aggregate ----------------
// One wave per (node, sign). lane covers channels (2*lane, 2*lane+1).
template <bool FP32IN>
__global__ __launch_bounds__(256) void agg_kernel(
    const void* __restrict__ featv,
    unsigned* __restrict__ aggp, unsigned* __restrict__ aggn,
    const int* __restrict__ row_p, const int* __restrict__ csr_p,
    const int* __restrict__ row_n, const int* __restrict__ csr_n, int nN) {
    const int t = threadIdx.x;
    const int wave = __builtin_amdgcn_readfirstlane(t >> 6);
    const int lane = t & 63;
    const int node = blockIdx.x * 2 + (wave >> 1);
    const int sign = wave & 1;
    if (node >= nN) return;
    const int* __restrict__ rowp = sign ? row_n : row_p;
    const int* __restrict__ csr = sign ? csr_n : csr_p;
    unsigned* __restrict__ out = sign ? aggn : aggp;
    const int s0 = rowp[node], s1 = rowp[node + 1];
    float ax = 0.f, ay = 0.f;
    int e = s0;
    if (FP32IN) {
        const float* feat = (const float*)featv;
        for (; e + 7 < s1; e += 8) {
            const int a0 = csr[e], a1 = csr[e+1], a2 = csr[e+2], a3 = csr[e+3];
            const int a4 = csr[e+4], a5 = csr[e+5], a6 = csr[e+6], a7 = csr[e+7];
            const float2 v0 = ((const float2*)(feat + (size_t)a0 * CH))[lane];
            const float2 v1 = ((const float2*)(feat + (size_t)a1 * CH))[lane];
            const float2 v2 = ((const float2*)(feat + (size_t)a2 * CH))[lane];
            const float2 v3 = ((const float2*)(feat + (size_t)a3 * CH))[lane];
            const float2 v4 = ((const float2*)(feat + (size_t)a4 * CH))[lane];
            const float2 v5 = ((const float2*)(feat + (size_t)a5 * CH))[lane];
            const float2 v6 = ((const float2*)(feat + (size_t)a6 * CH))[lane];
            const float2 v7 = ((const float2*)(feat + (size_t)a7 * CH))[lane];
            ax += ((v0.x + v1.x) + (v2.x + v3.x)) + ((v4.x + v5.x) + (v6.x + v7.x));
            ay += ((v0.y + v1.y) + (v2.y + v3.y)) + ((v4.y + v5.y) + (v6.y + v7.y));
        }
        for (; e + 1 < s1; e += 2) {
            const int a0 = csr[e], a1 = csr[e + 1];
            const float2 v0 = ((const float2*)(feat + (size_t)a0 * CH))[lane];
            const float2 v1 = ((const float2*)(feat + (size_t)a1 * CH))[lane];
            ax += v0.x + v1.x;
            ay += v0.y + v1.y;
        }
        if (e < s1) {
            const float2 v0 = ((const float2*)(feat + (size_t)csr[e] * CH))[lane];
            ax += v0.x; ay += v0.y;
        }
    } else {
        const unsigned short* feat = (const unsigned short*)featv;
        for (; e + 7 < s1; e += 8) {
            const int a0 = csr[e], a1 = csr[e+1], a2 = csr[e+2], a3 = csr[e+3];
            const int a4 = csr[e+4], a5 = csr[e+5], a6 = csr[e+6], a7 = csr[e+7];
            const unsigned v0 = ((const unsigned*)(feat + (size_t)a0 * CH))[lane];
            const unsigned v1 = ((const unsigned*)(feat + (size_t)a1 * CH))[lane];
            const unsigned v2 = ((const unsigned*)(feat + (size_t)a2 * CH))[lane];
            const unsigned v3 = ((const unsigned*)(feat + (size_t)a3 * CH))[lane];
            const unsigned v4 = ((const unsigned*)(feat + (size_t)a4 * CH))[lane];
            const unsigned v5 = ((const unsigned*)(feat + (size_t)a5 * CH))[lane];
            const unsigned v6 = ((const unsigned*)(feat + (size_t)a6 * CH))[lane];
            const unsigned v7 = ((const unsigned*)(feat + (size_t)a7 * CH))[lane];
            ax += ((bf_lo(v0) + bf_lo(v1)) + (bf_lo(v2) + bf_lo(v3))) +
                  ((bf_lo(v4) + bf_lo(v5)) + (bf_lo(v6) + bf_lo(v7)));
            ay += ((bf_hi(v0) + bf_hi(v1)) + (bf_hi(v2) + bf_hi(v3))) +
                  ((bf_hi(v4) + bf_hi(v5)) + (bf_hi(v6) + bf_hi(v7)));
        }
        for (; e + 1 < s1; e += 2) {
            const unsigned v0 = ((const unsigned*)(feat + (size_t)csr[e] * CH))[lane];
            const unsigned v1 = ((const unsigned*)(feat + (size_t)csr[e + 1] * CH))[lane];
            ax += bf_lo(v0) + bf_lo(v1);
            ay += bf_hi(v0) + bf_hi(v1);
        }
        if (e < s1) {
            const unsigned v0 = ((const unsigned*)(feat + (size_t)csr[e] * CH))[lane];
            ax += bf_lo(v0); ay += bf_hi(v0);
        }
    }
    const int d = s1 - s0;
    const float inv = 1.0f / (float)(d > 1 ? d : 1);
    ax *= inv; ay *= inv;
    out[(size_t)node * 64 + lane] = (unsigned)f2bf(ax) | ((unsigned)f2bf(ay) << 16);
}

// ---------------- weight packing ----------------
__global__ __launch_bounds__(64) void wpack_kernel(
    const float* __restrict__ Wp_l, const float* __restrict__ Wp_r,
    const float* __restrict__ Wn_l, const float* __restrict__ Wn_r,
    const float* __restrict__ Wl_pos, const float* __restrict__ Wr_pos,
    const float* __restrict__ Wl_neg, const float* __restrict__ Wr_neg,
    unsigned short* __restrict__ Wpk) {
    const int b = blockIdx.x;  // 0..287 = L*96 + ks*8 + nt
    const int L = b / 96;
    const int rem = b % 96;
    const int ks = rem / 8, nt = rem % 8;
    const int lane = threadIdx.x;
    const int kb = ks * 32 + (lane >> 4) * 8;
    const int n = nt * 16 + (lane & 15);
    unsigned short v[8];
#pragma unroll
    for (int j = 0; j < 8; ++j) {
        const int k = kb + j;
        float w = 0.f;
        if (L == 0) {
            if (k < 128)      w = (n < 64) ? Wp_l[k * 64 + n] : 0.f;
            else if (k < 256) w = (n < 64) ? 0.f : Wn_l[(k - 128) * 64 + (n - 64)];
            else              w = (n < 64) ? Wp_r[(k - 256) * 64 + n]
                                           : Wn_r[(k - 256) * 64 + (n - 64)];
        } else {
            const float* WLp = Wl_pos + (size_t)(L - 1) * 128 * 64;
            const float* WLn = Wl_neg + (size_t)(L - 1) * 128 * 64;
            const float* WRp = Wr_pos + (size_t)(L - 1) * 64 * 64;
            const float* WRn = Wr_neg + (size_t)(L - 1) * 64 * 64;
            if (k < 64)       w = (n < 64) ? WLp[k * 64 + n] : 0.f;
            else if (k < 128) w = (n < 64) ? 0.f : WLn[(k - 64) * 64 + (n - 64)];
            else if (k < 192) w = (n < 64) ? 0.f : WLn[(64 + k - 128) * 64 + (n - 64)];
            else if (k < 256) w = (n < 64) ? WLp[(64 + k - 192) * 64 + n] : 0.f;
            else if (k < 320) w = (n < 64) ? WRp[(k - 256) * 64 + n] : 0.f;
            else              w = (n < 64) ? 0.f : WRn[(k - 320) * 64 + (n - 64)];
        }
        v[j] = f2bf(w);
    }
    unsigned short* dst = Wpk + (size_t)b * 512 + lane * 8;
#pragma unroll
    for (int j = 0; j < 8; ++j) dst[j] = v[j];
}

__global__ void bcat_kernel(const float* __restrict__ bp, const float* __restrict__ bn,
                            const float* __restrict__ b_pos, const float* __restrict__ b_neg,
                            float* __restrict__ bcat) {
    int t = threadIdx.x;  // 384
    int L = t >> 7, n = t & 127;
    float v;
    if (L == 0) v = (n < 64) ? bp[n] : bn[n - 64];
    else        v = (n < 64) ? b_pos[(L - 1) * 64 + n] : b_neg[(L - 1) * 64 + (n - 64)];
    bcat[t] = v;
}

// ---------------- MFMA GEMM: z = tanh([aggp|aggn|feat] @ Wcat + bcat) ----------------
template <bool XF32, bool OUTF32>
__global__ __launch_bounds__(256) void gemm_kernel(
    const unsigned short* __restrict__ aggp, const unsigned short* __restrict__ aggn,
    const void* __restrict__ featv, const unsigned short* __restrict__ Wpk,
    const float* __restrict__ bcat, void* __restrict__ outv, int nN) {
    const int t = threadIdx.x;
    const int wave = __builtin_amdgcn_readfirstlane(t >> 6);
    const int lane = t & 63;
    const int r0 = blockIdx.x * 64 + wave * 16;
    int rowA = r0 + (lane & 15);
    if (rowA >= nN) rowA = nN - 1;  // clamp loads; stores guarded
    const int koff = (lane >> 4) * 8;

    f32x4 acc[8];
#pragma unroll
    for (int i = 0; i < 8; ++i) acc[i] = (f32x4){0.f, 0.f, 0.f, 0.f};

#pragma unroll
    for (int ks = 0; ks < 12; ++ks) {
        const int kcol = (ks & 3) * 32 + koff;
        bf16x8 a;
        if (ks < 4) {
            a = *(const bf16x8*)(aggp + (size_t)rowA * CH + kcol);
        } else if (ks < 8) {
            a = *(const bf16x8*)(aggn + (size_t)rowA * CH + kcol);
        } else if (XF32) {
            const float* p = (const float*)featv + (size_t)rowA * CH + kcol;
            const float4 u0 = *(const float4*)(p);
            const float4 u1 = *(const float4*)(p + 4);
            union { bf16x8 v; unsigned short u[8]; } au;
            au.u[0] = f2bf(u0.x); au.u[1] = f2bf(u0.y);
            au.u[2] = f2bf(u0.z); au.u[3] = f2bf(u0.w);
            au.u[4] = f2bf(u1.x); au.u[5] = f2bf(u1.y);
            au.u[6] = f2bf(u1.z); au.u[7] = f2bf(u1.w);
            a = au.v;
        } else {
            a = *(const bf16x8*)((const unsigned short*)featv + (size_t)rowA * CH + kcol);
        }
        const unsigned short* wb = Wpk + (size_t)(ks * 8) * 512 + lane * 8;
#pragma unroll
        for (int nt = 0; nt < 8; ++nt) {
            const bf16x8 bfr = *(const bf16x8*)(wb + nt * 512);
            acc[nt] = __builtin_amdgcn_mfma_f32_16x16x32_bf16(a, bfr, acc[nt], 0, 0, 0);
        }
    }

    const int col0 = lane & 15;
    const int rq = (lane >> 4) * 4;
#pragma unroll
    for (int nt = 0; nt < 8; ++nt) {
        const int col = nt * 16 + col0;
        const float bias = bcat[col];
#pragma unroll
        for (int r = 0; r < 4; ++r) {
            const int row = r0 + rq + r;
            if (row < nN) {
                const float v = fast_tanh(acc[nt][r] + bias);
                if (OUTF32) ((float*)outv)[(size_t)row * CH + col] = v;
                else ((unsigned short*)outv)[(size_t)row * CH + col] = f2bf(v);
            }
        }
    }
}

// ---------------- launch ----------------
extern "C" void kernel_launch(void* const* d_in, const int* in_sizes, int n_in,
                              void* d_out, int out_size, void* d_ws, size_t ws_size,
                              hipStream_t stream) {
    const float* x      = (const float*)d_in[0];
    const int*   pe     = (const int*)d_in[1];  // [2][E] src,dst
    const int*   ne     = (const int*)d_in[2];
    const float* Wp_l   = (const float*)d_in[3];
    const float* Wp_r   = (const float*)d_in[4];
    const float* bp     = (const float*)d_in[5];
    const float* Wn_l   = (const float*)d_in[6];
    const float* Wn_r   = (const float*)d_in[7];
    const float* bn     = (const float*)d_in[8];
    const float* Wl_pos = (const float*)d_in[9];
    const float* Wr_pos = (const float*)d_in[10];
    const float* b_pos  = (const float*)d_in[11];
    const float* Wl_neg = (const float*)d_in[12];
    const float* Wr_neg = (const float*)d_in[13];
    const float* b_neg  = (const float*)d_in[14];

    const int E = in_sizes[1] / 2;
    const int n = in_sizes[0] / CH;

    const int NBr = (n + BNODES - 1) >> BSHIFT;        // buckets per sign (196)
    const int G   = (E + CHUNKE - 1) / CHUNKE;         // chunks per sign (74)
    const int M   = NBr * G;                           // hist entries per sign

    // workspace layout
    unsigned short* A    = (unsigned short*)d_ws;   // n*128 bf16
    unsigned short* B    = A + (size_t)n * CH;
    unsigned short* C    = B + (size_t)n * CH;
    unsigned short* Wpk  = C + (size_t)n * CH;      // 3*96*512 = 147456
    float* bcat  = (float*)(Wpk + 147456);          // 384
    int* row_p   = (int*)(bcat + 384);              // n+1
    int* row_n   = row_p + n + 1;                   // n+1
    int* csr_p   = row_n + n + 1;                   // E
    int* csr_n   = csr_p + E;                       // E
    int* hb      = csr_n + E;                       // 2*M
    // packed edge temp (2E ints = 8E bytes) aliases C: C is first written by
    // layer-1 agg, strictly after bucket_kernel completes (stream order).
    int* tmp     = (int*)C;

    // CSR build: no global atomics, no memset
    hist_kernel<<<dim3(G, 2), 256, 0, stream>>>(pe, ne, hb, NBr, G, M, E);
    wpack_kernel<<<288, 64, 0, stream>>>(Wp_l, Wp_r, Wn_l, Wn_r,
                                         Wl_pos, Wr_pos, Wl_neg, Wr_neg, Wpk);
    bcat_kernel<<<1, 384, 0, stream>>>(bp, bn, b_pos, b_neg, bcat);
    hscan_kernel<<<dim3(1, 2), 1024, 0, stream>>>(hb, M);
    scatter_kernel<<<dim3(G, 2), 256, 0, stream>>>(pe, ne, hb, tmp, NBr, G, M, E);
    bucket_kernel<<<dim3(NBr, 2), 256, 0, stream>>>(tmp, hb, row_p, row_n,
                                                    csr_p, csr_n, NBr, G, M, E, n);

    const dim3 agrid((n + 1) / 2), ablock(256);
    const dim3 ggrid((n + 63) / 64), gblock(256);

    // L0: agg(x) -> A,B ; gemm(A,B,x) -> z1 in A
    agg_kernel<true><<<agrid, ablock, 0, stream>>>(
        x, (unsigned*)A, (unsigned*)B, row_p, csr_p, row_n, csr_n, n);
    gemm_kernel<true, false><<<ggrid, gblock, 0, stream>>>(
        A, B, x, Wpk, bcat, A, n);
    // L1: agg(A) -> B,C ; gemm(B,C,A) -> z2 in B
    agg_kernel<false><<<agrid, ablock, 0, stream>>>(
        A, (unsigned*)B, (unsigned*)C, row_p, csr_p, row_n, csr_n, n);
    gemm_kernel<false, false><<<ggrid, gblock, 0, stream>>>(
        B, C, A, Wpk + 96 * 512, bcat + 128, B, n);
    // L2: agg(B) -> A,C ; gemm(A,C,B) -> d_out fp32
    agg_kernel<false><<<agrid, ablock, 0, stream>>>(
        B, (unsigned*)A, (unsigned*)C, row_p, csr_p, row_n, csr_n, n);
    gemm_kernel<false, true><<<ggrid, gblock, 0, stream>>>(
        A, C, B, Wpk + 2 * 96 * 512, bcat + 256, d_out, n);
}

// Round 5
// 637.428 us; speedup vs baseline: 2.0533x; 1.0898x over previous
//
#include <hip/hip_runtime.h>
#include <math.h>

#define CH 128
#define BSHIFT 9                  // 512 nodes per bucket
#define BNODES (1 << BSHIFT)
#define CHUNKE 16384              // edges per hist/scatter block

typedef __attribute__((ext_vector_type(8))) short bf16x8;
typedef __attribute__((ext_vector_type(4))) float f32x4;

// ---------------- CSR build: atomic-free counting sort ----------------
__global__ __launch_bounds__(256) void hist_kernel(const int* __restrict__ pe,
                                                   const int* __restrict__ ne,
                                                   int* __restrict__ hb,
                                                   int NBr, int G, int M, int E) {
    const int g = blockIdx.x, s = blockIdx.y, t = threadIdx.x;
    const int* __restrict__ dst = (s ? ne : pe) + E;
    __shared__ int h[512];                      // NBr <= 512
    for (int i = t; i < NBr; i += 256) h[i] = 0;
    __syncthreads();
    const int e0 = g * CHUNKE, e1 = min(e0 + CHUNKE, E);
    for (int e = e0 + t; e < e1; e += 256) atomicAdd(&h[dst[e] >> BSHIFT], 1);
    __syncthreads();
    int* out = hb + (size_t)s * M;
    for (int b = t; b < NBr; b += 256) out[b * G + g] = h[b];
}

__global__ __launch_bounds__(1024) void hscan_kernel(int* __restrict__ hb, int M) {
    const int s = blockIdx.y, t = threadIdx.x;
    int* H = hb + (size_t)s * M;
    const int K = (M + 1023) >> 10;
    const int i0 = t * K, i1 = min(i0 + K, M);
    int sum = 0;
    for (int i = i0; i < i1; ++i) sum += H[i];
    __shared__ int sh[1024];
    sh[t] = sum;
    __syncthreads();
    for (int off = 1; off < 1024; off <<= 1) {
        int v = (t >= off) ? sh[t - off] : 0;
        __syncthreads();
        sh[t] += v;
        __syncthreads();
    }
    int run = sh[t] - sum;
    for (int i = i0; i < i1; ++i) { int v = H[i]; H[i] = run; run += v; }
}

__global__ __launch_bounds__(256) void scatter_kernel(const int* __restrict__ pe,
                                                      const int* __restrict__ ne,
                                                      const int* __restrict__ hb,
                                                      int* __restrict__ tmp,
                                                      int NBr, int G, int M, int E) {
    const int g = blockIdx.x, s = blockIdx.y, t = threadIdx.x;
    const int* __restrict__ ed = s ? ne : pe;
    const int* off = hb + (size_t)s * M;
    __shared__ int cur[512];
    for (int b = t; b < NBr; b += 256) cur[b] = off[b * G + g];
    __syncthreads();
    int* out = tmp + (size_t)s * E;
    const int e0 = g * CHUNKE, e1 = min(e0 + CHUNKE, E);
    for (int e = e0 + t; e < e1; e += 256) {
        const int src = ed[e], d = ed[E + e];
        const int p = atomicAdd(&cur[d >> BSHIFT], 1);   // LDS atomic
        out[p] = (src << BSHIFT) | (d & (BNODES - 1));
    }
}

__global__ __launch_bounds__(256) void bucket_kernel(const int* __restrict__ tmp,
                                                     const int* __restrict__ hb,
                                                     int* __restrict__ row_p,
                                                     int* __restrict__ row_n,
                                                     int* __restrict__ csr_p,
                                                     int* __restrict__ csr_n,
                                                     int NBr, int G, int M, int E, int nN) {
    const int b = blockIdx.x, s = blockIdx.y, t = threadIdx.x;
    const int* off = hb + (size_t)s * M;
    const int lo = off[b * G];
    const int hi = (b + 1 < NBr) ? off[(b + 1) * G] : E;
    const int base = b << BSHIFT;
    const int nloc = min(BNODES, nN - base);
    const int* __restrict__ in = tmp + (size_t)s * E;
    int* __restrict__ row = s ? row_n : row_p;
    int* __restrict__ csr = s ? csr_n : csr_p;
    __shared__ int cnt[BNODES];
    __shared__ int psum[256];
    for (int i = t; i < BNODES; i += 256) cnt[i] = 0;
    __syncthreads();
    for (int e = lo + t; e < hi; e += 256) atomicAdd(&cnt[in[e] & (BNODES - 1)], 1);
    __syncthreads();
    const int c0 = cnt[2 * t], c1 = cnt[2 * t + 1];
    const int ps = c0 + c1;
    psum[t] = ps;
    __syncthreads();
    for (int o = 1; o < 256; o <<= 1) {
        int v = (t >= o) ? psum[t - o] : 0;
        __syncthreads();
        psum[t] += v;
        __syncthreads();
    }
    const int ex = psum[t] - ps;
    cnt[2 * t]     = lo + ex;        // becomes write cursor
    cnt[2 * t + 1] = lo + ex + c0;
    if (2 * t < nloc)     row[base + 2 * t] = lo + ex;
    if (2 * t + 1 < nloc) row[base + 2 * t + 1] = lo + ex + c0;
    if (b == NBr - 1 && t == 0) row[nN] = E;
    __syncthreads();
    for (int e = lo + t; e < hi; e += 256) {
        const int v = in[e];
        const int p = atomicAdd(&cnt[v & (BNODES - 1)], 1);  // LDS atomic
        csr[p] = v >> BSHIFT;
    }
}

// ---------------- helpers ----------------
__device__ __forceinline__ float fast_tanh(float x) {
    float e = __expf(2.0f * x);
    return 1.0f - 2.0f * __builtin_amdgcn_rcpf(e + 1.0f);
}

__device__ __forceinline__ unsigned short f2bf(float f) {  // RNE
    unsigned u = __float_as_uint(f);
    u += 0x7fffu + ((u >> 16) & 1u);
    return (unsigned short)(u >> 16);
}

__device__ __forceinline__ float bf_lo(unsigned v) { return __uint_as_float(v << 16); }
__device__ __forceinline__ float bf_hi(unsigned v) { return __uint_as_float(v & 0xffff0000u); }

// ---------------- x -> bf16 convert (once) ----------------
__global__ __launch_bounds__(256) void cvt_kernel(const float* __restrict__ x,
                                                  unsigned short* __restrict__ xb,
                                                  int total8) {
    const int i = blockIdx.x * 256 + threadIdx.x;
    if (i >= total8) return;
    const float4 u0 = ((const float4*)x)[2 * i];
    const float4 u1 = ((const float4*)x)[2 * i + 1];
    union { bf16x8 v; unsigned short u[8]; } o;
    o.u[0] = f2bf(u0.x); o.u[1] = f2bf(u0.y); o.u[2] = f2bf(u0.z); o.u[3] = f2bf(u0.w);
    o.u[4] = f2bf(u1.x); o.u[5] = f2bf(u1.y); o.u[6] = f2bf(u1.z); o.u[7] = f2bf(u1.w);
    ((bf16x8*)xb)[i] = o.v;
}

// ---------------- aggregate ----------------
// One wave per node, BOTH signs interleaved -> up to 16 independent row
// gathers in flight (latency hiding). lane covers channels (2l, 2l+1).
#define G8(csr, e, ax, ay) { \
    const int a0 = csr[e], a1 = csr[e+1], a2 = csr[e+2], a3 = csr[e+3]; \
    const int a4 = csr[e+4], a5 = csr[e+5], a6 = csr[e+6], a7 = csr[e+7]; \
    const unsigned w0 = ((const unsigned*)(feat + (size_t)a0 * CH))[lane]; \
    const unsigned w1 = ((const unsigned*)(feat + (size_t)a1 * CH))[lane]; \
    const unsigned w2 = ((const unsigned*)(feat + (size_t)a2 * CH))[lane]; \
    const unsigned w3 = ((const unsigned*)(feat + (size_t)a3 * CH))[lane]; \
    const unsigned w4 = ((const unsigned*)(feat + (size_t)a4 * CH))[lane]; \
    const unsigned w5 = ((const unsigned*)(feat + (size_t)a5 * CH))[lane]; \
    const unsigned w6 = ((const unsigned*)(feat + (size_t)a6 * CH))[lane]; \
    const unsigned w7 = ((const unsigned*)(feat + (size_t)a7 * CH))[lane]; \
    ax += ((bf_lo(w0) + bf_lo(w1)) + (bf_lo(w2) + bf_lo(w3))) + \
          ((bf_lo(w4) + bf_lo(w5)) + (bf_lo(w6) + bf_lo(w7))); \
    ay += ((bf_hi(w0) + bf_hi(w1)) + (bf_hi(w2) + bf_hi(w3))) + \
          ((bf_hi(w4) + bf_hi(w5)) + (bf_hi(w6) + bf_hi(w7))); }

#define G4(csr, e, ax, ay) { \
    const int a0 = csr[e], a1 = csr[e+1], a2 = csr[e+2], a3 = csr[e+3]; \
    const unsigned w0 = ((const unsigned*)(feat + (size_t)a0 * CH))[lane]; \
    const unsigned w1 = ((const unsigned*)(feat + (size_t)a1 * CH))[lane]; \
    const unsigned w2 = ((const unsigned*)(feat + (size_t)a2 * CH))[lane]; \
    const unsigned w3 = ((const unsigned*)(feat + (size_t)a3 * CH))[lane]; \
    ax += (bf_lo(w0) + bf_lo(w1)) + (bf_lo(w2) + bf_lo(w3)); \
    ay += (bf_hi(w0) + bf_hi(w1)) + (bf_hi(w2) + bf_hi(w3)); }

#define G1(csr, e, ax, ay) { \
    const unsigned w0 = ((const unsigned*)(feat + (size_t)csr[e] * CH))[lane]; \
    ax += bf_lo(w0); ay += bf_hi(w0); }

__global__ __launch_bounds__(256) void agg_kernel(
    const unsigned short* __restrict__ feat,
    unsigned* __restrict__ aggp, unsigned* __restrict__ aggn,
    const int* __restrict__ row_p, const int* __restrict__ csr_p,
    const int* __restrict__ row_n, const int* __restrict__ csr_n, int nN) {
    const int t = threadIdx.x;
    const int wave = t >> 6;
    const int lane = t & 63;
    const int node = blockIdx.x * 4 + wave;
    if (node >= nN) return;
    int ep = row_p[node]; const int e1p = row_p[node + 1];
    int en = row_n[node]; const int e1n = row_n[node + 1];
    const int degp = e1p - ep;
    const int degn = e1n - en;
    float axp = 0.f, ayp = 0.f, axn = 0.f, ayn = 0.f;
    // joint main: 16 row loads in flight
    while (ep + 8 <= e1p && en + 8 <= e1n) {
        G8(csr_p, ep, axp, ayp);
        G8(csr_n, en, axn, ayn);
        ep += 8; en += 8;
    }
    // joint mid: 8 in flight
    while (ep + 4 <= e1p && en + 4 <= e1n) {
        G4(csr_p, ep, axp, ayp);
        G4(csr_n, en, axn, ayn);
        ep += 4; en += 4;
    }
    // per-sign drains
    for (; ep + 7 < e1p; ep += 8) G8(csr_p, ep, axp, ayp);
    if (ep + 3 < e1p) { G4(csr_p, ep, axp, ayp); ep += 4; }
    for (; ep < e1p; ++ep) G1(csr_p, ep, axp, ayp);
    for (; en + 7 < e1n; en += 8) G8(csr_n, en, axn, ayn);
    if (en + 3 < e1n) { G4(csr_n, en, axn, ayn); en += 4; }
    for (; en < e1n; ++en) G1(csr_n, en, axn, ayn);

    const float invp = 1.0f / (float)(degp > 1 ? degp : 1);
    const float invn = 1.0f / (float)(degn > 1 ? degn : 1);
    aggp[(size_t)node * 64 + lane] = (unsigned)f2bf(axp * invp) | ((unsigned)f2bf(ayp * invp) << 16);
    aggn[(size_t)node * 64 + lane] = (unsigned)f2bf(axn * invn) | ((unsigned)f2bf(ayn * invn) << 16);
}

// ---------------- weight packing ----------------
__global__ __launch_bounds__(64) void wpack_kernel(
    const float* __restrict__ Wp_l, const float* __restrict__ Wp_r,
    const float* __restrict__ Wn_l, const float* __restrict__ Wn_r,
    const float* __restrict__ Wl_pos, const float* __restrict__ Wr_pos,
    const float* __restrict__ Wl_neg, const float* __restrict__ Wr_neg,
    unsigned short* __restrict__ Wpk) {
    const int b = blockIdx.x;  // 0..287 = L*96 + ks*8 + nt
    const int L = b / 96;
    const int rem = b % 96;
    const int ks = rem / 8, nt = rem % 8;
    const int lane = threadIdx.x;
    const int kb = ks * 32 + (lane >> 4) * 8;
    const int n = nt * 16 + (lane & 15);
    unsigned short v[8];
#pragma unroll
    for (int j = 0; j < 8; ++j) {
        const int k = kb + j;
        float w = 0.f;
        if (L == 0) {
            if (k < 128)      w = (n < 64) ? Wp_l[k * 64 + n] : 0.f;
            else if (k < 256) w = (n < 64) ? 0.f : Wn_l[(k - 128) * 64 + (n - 64)];
            else              w = (n < 64) ? Wp_r[(k - 256) * 64 + n]
                                           : Wn_r[(k - 256) * 64 + (n - 64)];
        } else {
            const float* WLp = Wl_pos + (size_t)(L - 1) * 128 * 64;
            const float* WLn = Wl_neg + (size_t)(L - 1) * 128 * 64;
            const float* WRp = Wr_pos + (size_t)(L - 1) * 64 * 64;
            const float* WRn = Wr_neg + (size_t)(L - 1) * 64 * 64;
            if (k < 64)       w = (n < 64) ? WLp[k * 64 + n] : 0.f;
            else if (k < 128) w = (n < 64) ? 0.f : WLn[(k - 64) * 64 + (n - 64)];
            else if (k < 192) w = (n < 64) ? 0.f : WLn[(64 + k - 128) * 64 + (n - 64)];
            else if (k < 256) w = (n < 64) ? WLp[(64 + k - 192) * 64 + n] : 0.f;
            else if (k < 320) w = (n < 64) ? WRp[(k - 256) * 64 + n] : 0.f;
            else              w = (n < 64) ? 0.f : WRn[(k - 320) * 64 + (n - 64)];
        }
        v[j] = f2bf(w);
    }
    unsigned short* dst = Wpk + (size_t)b * 512 + lane * 8;
#pragma unroll
    for (int j = 0; j < 8; ++j) dst[j] = v[j];
}

__global__ void bcat_kernel(const float* __restrict__ bp, const float* __restrict__ bn,
                            const float* __restrict__ b_pos, const float* __restrict__ b_neg,
                            float* __restrict__ bcat) {
    int t = threadIdx.x;  // 384
    int L = t >> 7, n = t & 127;
    float v;
    if (L == 0) v = (n < 64) ? bp[n] : bn[n - 64];
    else        v = (n < 64) ? b_pos[(L - 1) * 64 + n] : b_neg[(L - 1) * 64 + (n - 64)];
    bcat[t] = v;
}

// ---------------- MFMA GEMM: z = tanh([aggp|aggn|feat] @ Wcat + bcat) ----------------
// All inputs bf16 now (xb pre-converted). In-place safe per 16-row wave band.
template <bool OUTF32>
__global__ __launch_bounds__(256) void gemm_kernel(
    const unsigned short* __restrict__ aggp, const unsigned short* __restrict__ aggn,
    const unsigned short* __restrict__ feat, const unsigned short* __restrict__ Wpk,
    const float* __restrict__ bcat, void* __restrict__ outv, int nN) {
    const int t = threadIdx.x;
    const int wave = __builtin_amdgcn_readfirstlane(t >> 6);
    const int lane = t & 63;
    const int r0 = blockIdx.x * 64 + wave * 16;
    int rowA = r0 + (lane & 15);
    if (rowA >= nN) rowA = nN - 1;  // clamp loads; stores guarded
    const int koff = (lane >> 4) * 8;

    f32x4 acc[8];
#pragma unroll
    for (int i = 0; i < 8; ++i) acc[i] = (f32x4){0.f, 0.f, 0.f, 0.f};

#pragma unroll
    for (int ks = 0; ks < 12; ++ks) {
        const int kcol = (ks & 3) * 32 + koff;
        const unsigned short* ap = (ks < 4) ? aggp : (ks < 8) ? aggn : feat;
        const bf16x8 a = *(const bf16x8*)(ap + (size_t)rowA * CH + kcol);
        const unsigned short* wb = Wpk + (size_t)(ks * 8) * 512 + lane * 8;
#pragma unroll
        for (int nt = 0; nt < 8; ++nt) {
            const bf16x8 bfr = *(const bf16x8*)(wb + nt * 512);
            acc[nt] = __builtin_amdgcn_mfma_f32_16x16x32_bf16(a, bfr, acc[nt], 0, 0, 0);
        }
    }

    const int col0 = lane & 15;
    const int rq = (lane >> 4) * 4;
#pragma unroll
    for (int nt = 0; nt < 8; ++nt) {
        const int col = nt * 16 + col0;
        const float bias = bcat[col];
#pragma unroll
        for (int r = 0; r < 4; ++r) {
            const int row = r0 + rq + r;
            if (row < nN) {
                const float v = fast_tanh(acc[nt][r] + bias);
                if (OUTF32) ((float*)outv)[(size_t)row * CH + col] = v;
                else ((unsigned short*)outv)[(size_t)row * CH + col] = f2bf(v);
            }
        }
    }
}

// ---------------- launch ----------------
extern "C" void kernel_launch(void* const* d_in, const int* in_sizes, int n_in,
                              void* d_out, int out_size, void* d_ws, size_t ws_size,
                              hipStream_t stream) {
    const float* x      = (const float*)d_in[0];
    const int*   pe     = (const int*)d_in[1];  // [2][E] src,dst
    const int*   ne     = (const int*)d_in[2];
    const float* Wp_l   = (const float*)d_in[3];
    const float* Wp_r   = (const float*)d_in[4];
    const float* bp     = (const float*)d_in[5];
    const float* Wn_l   = (const float*)d_in[6];
    const float* Wn_r   = (const float*)d_in[7];
    const float* bn     = (const float*)d_in[8];
    const float* Wl_pos = (const float*)d_in[9];
    const float* Wr_pos = (const float*)d_in[10];
    const float* b_pos  = (const float*)d_in[11];
    const float* Wl_neg = (const float*)d_in[12];
    const float* Wr_neg = (const float*)d_in[13];
    const float* b_neg  = (const float*)d_in[14];

    const int E = in_sizes[1] / 2;
    const int n = in_sizes[0] / CH;

    const int NBr = (n + BNODES - 1) >> BSHIFT;        // buckets per sign (196)
    const int G   = (E + CHUNKE - 1) / CHUNKE;         // chunks per sign (74)
    const int M   = NBr * G;                           // hist entries per sign

    // workspace layout
    unsigned short* A    = (unsigned short*)d_ws;   // n*128 bf16
    unsigned short* B    = A + (size_t)n * CH;
    unsigned short* C    = B + (size_t)n * CH;
    unsigned short* Wpk  = C + (size_t)n * CH;      // 3*96*512 = 147456
    float* bcat  = (float*)(Wpk + 147456);          // 384
    int* row_p   = (int*)(bcat + 384);              // n+1
    int* row_n   = row_p + n + 1;                   // n+1
    int* csr_p   = row_n + n + 1;                   // E
    int* csr_n   = csr_p + E;                       // E
    int* hb      = csr_n + E;                       // 2*M
    // packed edge temp (2E ints) aliases C during CSR build; afterwards the
    // same region holds xb (bf16 of x) until gemm0 completes; then C becomes
    // the L1 agg output. All transitions stream-ordered -> safe.
    int* tmp     = (int*)C;
    unsigned short* xb = C;

    // CSR build: no global atomics, no memset
    hist_kernel<<<dim3(G, 2), 256, 0, stream>>>(pe, ne, hb, NBr, G, M, E);
    wpack_kernel<<<288, 64, 0, stream>>>(Wp_l, Wp_r, Wn_l, Wn_r,
                                         Wl_pos, Wr_pos, Wl_neg, Wr_neg, Wpk);
    bcat_kernel<<<1, 384, 0, stream>>>(bp, bn, b_pos, b_neg, bcat);
    hscan_kernel<<<dim3(1, 2), 1024, 0, stream>>>(hb, M);
    scatter_kernel<<<dim3(G, 2), 256, 0, stream>>>(pe, ne, hb, tmp, NBr, G, M, E);
    bucket_kernel<<<dim3(NBr, 2), 256, 0, stream>>>(tmp, hb, row_p, row_n,
                                                    csr_p, csr_n, NBr, G, M, E, n);
    // x -> bf16 (after CSR build so xb can overwrite tmp)
    const int total8 = n * CH / 8;
    cvt_kernel<<<(total8 + 255) / 256, 256, 0, stream>>>(x, xb, total8);

    const dim3 agrid((n + 3) / 4), ablock(256);
    const dim3 ggrid((n + 63) / 64), gblock(256);

    // L0: agg(xb) -> A,B ; gemm(A,B,xb) -> z1 in A
    agg_kernel<<<agrid, ablock, 0, stream>>>(
        xb, (unsigned*)A, (unsigned*)B, row_p, csr_p, row_n, csr_n, n);
    gemm_kernel<false><<<ggrid, gblock, 0, stream>>>(
        A, B, xb, Wpk, bcat, A, n);
    // L1: agg(A) -> B,C ; gemm(B,C,A) -> z2 in B
    agg_kernel<<<agrid, ablock, 0, stream>>>(
        A, (unsigned*)B, (unsigned*)C, row_p, csr_p, row_n, csr_n, n);
    gemm_kernel<false><<<ggrid, gblock, 0, stream>>>(
        B, C, A, Wpk + 96 * 512, bcat + 128, B, n);
    // L2: agg(B) -> A,C ; gemm(A,C,B) -> d_out fp32
    agg_kernel<<<agrid, ablock, 0, stream>>>(
        B, (unsigned*)A, (unsigned*)C, row_p, csr_p, row_n, csr_n, n);
    gemm_kernel<true><<<ggrid, gblock, 0, stream>>>(
        A, C, B, Wpk + 2 * 96 * 512, bcat + 256, d_out, n);
}